// Round 11
// baseline (111.973 us; speedup 1.0000x reference)
//
#include <hip/hip_runtime.h>
#include <hip/hip_bf16.h>

#define N_NODES 50000
#define N_EDGES 800000
#define N_FEATS 64
#define EB4     (N_EDGES / 4)     // 200000 int4 groups
#define NBUCK   256               // destination buckets
#define BRANGE  196               // nodes per bucket: 256*196 = 50176 >= 50000
#define CAPB    4096              // records per bucket: mean 3136, sigma ~56 -> +17 sigma
#define BZT     1024              // bucketize block size; 196 blocks * 1024 >= EB4

// ---------------- kernels ----------------

__global__ void k_zero_i(int* __restrict__ p, int n) {
    int i = blockIdx.x * blockDim.x + threadIdx.x;
    if (i < n) p[i] = 0;
}

// Single-batch bucketize: each thread owns exactly one int4 group of edges.
// Rank within (block,bucket) via LDS returning atomics; ONE global atomic per
// (block,bucket) reserves a contiguous run. Record = (local_col << 16) | src
// (src < 50000 < 2^16, local_col < 196) -> 4 B, written in ~64 B runs.
__global__ void __launch_bounds__(BZT) k_bucketize(
    const int* __restrict__ row, const int* __restrict__ col,
    int* __restrict__ gcur, unsigned* __restrict__ recs)
{
    __shared__ int s_cnt[NBUCK];
    __shared__ int s_base[NBUCK];
    const int t = threadIdx.x;
    if (t < NBUCK) s_cnt[t] = 0;
    __syncthreads();

    const int g = blockIdx.x * BZT + t;
    const bool valid = g < EB4;
    int4 c4, r4;
    int bk[4], rk[4];
    if (valid) {
        c4 = ((const int4*)col)[g];
        r4 = ((const int4*)row)[g];
        bk[0] = c4.x / BRANGE; rk[0] = atomicAdd(&s_cnt[bk[0]], 1);
        bk[1] = c4.y / BRANGE; rk[1] = atomicAdd(&s_cnt[bk[1]], 1);
        bk[2] = c4.z / BRANGE; rk[2] = atomicAdd(&s_cnt[bk[2]], 1);
        bk[3] = c4.w / BRANGE; rk[3] = atomicAdd(&s_cnt[bk[3]], 1);
    }
    __syncthreads();
    if (t < NBUCK) {
        int n = s_cnt[t];
        s_base[t] = n ? atomicAdd(&gcur[t], n) : 0;
    }
    __syncthreads();
    if (valid) {
        int cc[4] = {c4.x, c4.y, c4.z, c4.w};
        int rr[4] = {r4.x, r4.y, r4.z, r4.w};
        #pragma unroll
        for (int i = 0; i < 4; i++) {
            int slot = s_base[bk[i]] + rk[i];
            unsigned rec = ((unsigned)(cc[i] - bk[i] * BRANGE) << 16) | (unsigned)rr[i];
            if (slot < CAPB) recs[(size_t)bk[i] * CAPB + slot] = rec;
        }
    }
}

// Per-bucket prep: degree count (LDS, uint4 stream) -> dinv (global) ->
// z0 = dinv * (X @ W^T) via wave-per-node coalesced matvec (all 512 threads).
__global__ void __launch_bounds__(512) k_prep(
    const int* __restrict__ gcur, const unsigned* __restrict__ recs,
    const float* __restrict__ x, const float* __restrict__ w,
    float* __restrict__ dinv, float* __restrict__ z0)
{
    __shared__ int   s_cnt[BRANGE];
    __shared__ float s_dinv[BRANGE];
    const int t = threadIdx.x;
    const int blk = blockIdx.x;
    const int own0 = blk * BRANGE;
    if (t < BRANGE) s_cnt[t] = 0;
    __syncthreads();

    const int sz  = min(gcur[blk], CAPB);
    const int sz4 = sz >> 2;
    const uint4* rb4 = (const uint4*)(recs + (size_t)blk * CAPB);
    for (int e = t; e < sz4; e += 512) {
        uint4 r = rb4[e];
        atomicAdd(&s_cnt[r.x >> 16], 1);
        atomicAdd(&s_cnt[r.y >> 16], 1);
        atomicAdd(&s_cnt[r.z >> 16], 1);
        atomicAdd(&s_cnt[r.w >> 16], 1);
    }
    if (t < (sz & 3)) {
        unsigned r = recs[(size_t)blk * CAPB + (sz4 << 2) + t];
        atomicAdd(&s_cnt[r >> 16], 1);
    }
    __syncthreads();

    if (t < BRANGE) {
        float d = rsqrtf((float)(s_cnt[t] + 1));
        s_dinv[t] = d;
        int node = own0 + t;
        if (node < N_NODES) dinv[node] = d;
    }
    __syncthreads();

    // wave-per-node matvec: lane reads one of 64 consecutive feats (coalesced)
    {
        const int wave = t >> 6, lane = t & 63;
        const float wl = w[lane];
        for (int nl = wave; nl < BRANGE; nl += 8) {
            int node = own0 + nl;              // wave-uniform
            if (node >= N_NODES) break;
            float v = x[(size_t)node * N_FEATS + lane] * wl;
            #pragma unroll
            for (int off = 32; off > 0; off >>= 1) v += __shfl_down(v, off, 64);
            if (lane == 0) z0[node] = s_dinv[nl] * v;
        }
    }
}

// Hop: one WG per bucket; stream own records (uint4, coalesced), LDS f32
// accumulate over 196 owned nodes, finalize with self term + dinv scaling.
//   FINAL=false: out[i] = dinv^2 * (z[i] + sum)      (emits next z)
//   FINAL=true : out[i] = dinv   * (z[i] + sum) + b
template <bool FINAL>
__global__ void __launch_bounds__(512) k_hop(
    const int* __restrict__ gcur, const unsigned* __restrict__ recs,
    const float* __restrict__ dinv, const float* __restrict__ zin,
    float* __restrict__ out, const float* __restrict__ bptr)
{
    __shared__ float acc[BRANGE];
    const int t = threadIdx.x;
    const int blk = blockIdx.x;
    if (t < BRANGE) acc[t] = 0.0f;
    __syncthreads();
    const int sz  = min(gcur[blk], CAPB);
    const int sz4 = sz >> 2;
    const uint4* rb4 = (const uint4*)(recs + (size_t)blk * CAPB);
    for (int e = t; e < sz4; e += 512) {
        uint4 r = rb4[e];
        atomicAdd(&acc[r.x >> 16], zin[r.x & 0xFFFFu]);
        atomicAdd(&acc[r.y >> 16], zin[r.y & 0xFFFFu]);
        atomicAdd(&acc[r.z >> 16], zin[r.z & 0xFFFFu]);
        atomicAdd(&acc[r.w >> 16], zin[r.w & 0xFFFFu]);
    }
    if (t < (sz & 3)) {
        unsigned r = recs[(size_t)blk * CAPB + (sz4 << 2) + t];
        atomicAdd(&acc[r >> 16], zin[r & 0xFFFFu]);
    }
    __syncthreads();
    if (t < BRANGE) {
        int node = blk * BRANGE + t;
        if (node < N_NODES) {
            float d = dinv[node];
            float v = zin[node] + acc[t];
            out[node] = FINAL ? (d * v + bptr[0]) : (d * d * v);
        }
    }
}

// ---------------- launch ----------------

extern "C" void kernel_launch(void* const* d_in, const int* in_sizes, int n_in,
                              void* d_out, int out_size, void* d_ws, size_t ws_size,
                              hipStream_t stream) {
    const float* x  = (const float*)d_in[0];   // [N, 64]
    const int*   ei = (const int*)d_in[1];     // [2, E]
    const float* W  = (const float*)d_in[2];   // [1, 64]
    const float* b  = (const float*)d_in[3];   // [1]
    float* out = (float*)d_out;                // [N]

    const int* row = ei;                       // sources
    const int* col = ei + N_EDGES;             // destinations

    // ws: gcur[256] | recs[NBUCK*CAPB u32] (4 MB) | dinv[N] | z0[N] | z1[N]
    int*      gcur = (int*)d_ws;
    unsigned* recs = (unsigned*)(gcur + NBUCK);
    float*    dinv = (float*)(recs + (size_t)NBUCK * CAPB);
    float*    z0   = dinv + N_NODES;
    float*    z1   = z0 + N_NODES;

    k_zero_i<<<1, NBUCK, 0, stream>>>(gcur, NBUCK);
    k_bucketize<<<(EB4 + BZT - 1) / BZT, BZT, 0, stream>>>(row, col, gcur, recs);
    k_prep<<<NBUCK, 512, 0, stream>>>(gcur, recs, x, W, dinv, z0);

    k_hop<false><<<NBUCK, 512, 0, stream>>>(gcur, recs, dinv, z0, z1, nullptr); // hop 1
    k_hop<false><<<NBUCK, 512, 0, stream>>>(gcur, recs, dinv, z1, z0, nullptr); // hop 2
    k_hop<true ><<<NBUCK, 512, 0, stream>>>(gcur, recs, dinv, z0, out, b);      // hop 3
}

// Round 12
// 101.812 us; speedup vs baseline: 1.0998x; 1.0998x over previous
//
#include <hip/hip_runtime.h>
#include <hip/hip_bf16.h>

#define N_NODES 50000
#define N_EDGES 800000
#define N_FEATS 64
#define EB4     (N_EDGES / 4)     // 200000 int4 groups
#define NBUCK   256               // destination buckets
#define BRANGE  196               // nodes per bucket: 256*196 = 50176 >= 50000
#define CAPB    4096              // records per bucket: mean 3136, sigma ~56 -> +17 sigma
#define BZT     1024              // bucketize block size; 196 blocks * 1024 >= EB4
#define HOPT    1024              // hop block size (more waves to hide LDS-atomic latency)

// ---------------- kernels ----------------

// Single-batch bucketize: each thread owns exactly one int4 group of edges.
// Rank within (block,bucket) via LDS returning atomics; ONE global atomic per
// (block,bucket) reserves a contiguous run. Record = (local_col << 16) | src
// (src < 50000 < 2^16, local_col < 196) -> 4 B, written in ~64 B runs.
__global__ void __launch_bounds__(BZT) k_bucketize(
    const int* __restrict__ row, const int* __restrict__ col,
    int* __restrict__ gcur, unsigned* __restrict__ recs)
{
    __shared__ int s_cnt[NBUCK];
    __shared__ int s_base[NBUCK];
    const int t = threadIdx.x;
    if (t < NBUCK) s_cnt[t] = 0;
    __syncthreads();

    const int g = blockIdx.x * BZT + t;
    const bool valid = g < EB4;
    int4 c4, r4;
    int bk[4], rk[4];
    if (valid) {
        c4 = ((const int4*)col)[g];
        r4 = ((const int4*)row)[g];
        bk[0] = c4.x / BRANGE; rk[0] = atomicAdd(&s_cnt[bk[0]], 1);
        bk[1] = c4.y / BRANGE; rk[1] = atomicAdd(&s_cnt[bk[1]], 1);
        bk[2] = c4.z / BRANGE; rk[2] = atomicAdd(&s_cnt[bk[2]], 1);
        bk[3] = c4.w / BRANGE; rk[3] = atomicAdd(&s_cnt[bk[3]], 1);
    }
    __syncthreads();
    if (t < NBUCK) {
        int n = s_cnt[t];
        s_base[t] = n ? atomicAdd(&gcur[t], n) : 0;
    }
    __syncthreads();
    if (valid) {
        int cc[4] = {c4.x, c4.y, c4.z, c4.w};
        int rr[4] = {r4.x, r4.y, r4.z, r4.w};
        #pragma unroll
        for (int i = 0; i < 4; i++) {
            int slot = s_base[bk[i]] + rk[i];
            unsigned rec = ((unsigned)(cc[i] - bk[i] * BRANGE) << 16) | (unsigned)rr[i];
            if (slot < CAPB) recs[(size_t)bk[i] * CAPB + slot] = rec;
        }
    }
}

// Per-bucket prep (R9-proven): degree count (LDS, uint2 stream) -> dinv ->
// z0 = dinv * (X @ W^T) with thread-per-node float4 matvec (196 independent chains).
__global__ void __launch_bounds__(512) k_prep(
    const int* __restrict__ gcur, const unsigned* __restrict__ recs,
    const float* __restrict__ x, const float* __restrict__ w,
    float* __restrict__ dinv, float* __restrict__ z0)
{
    __shared__ int   s_cnt[BRANGE];
    __shared__ float s_dinv[BRANGE];
    const int t = threadIdx.x;
    const int blk = blockIdx.x;
    const int own0 = blk * BRANGE;
    if (t < BRANGE) s_cnt[t] = 0;
    __syncthreads();

    const int sz  = min(gcur[blk], CAPB);
    const int sz2 = sz >> 1;
    const uint2* rb2 = (const uint2*)(recs + (size_t)blk * CAPB);
    for (int e = t; e < sz2; e += 512) {
        uint2 r = rb2[e];
        atomicAdd(&s_cnt[r.x >> 16], 1);
        atomicAdd(&s_cnt[r.y >> 16], 1);
    }
    if (t == 0 && (sz & 1)) {
        unsigned r = recs[(size_t)blk * CAPB + sz - 1];
        atomicAdd(&s_cnt[r >> 16], 1);
    }
    __syncthreads();

    if (t < BRANGE) {
        float d = rsqrtf((float)(s_cnt[t] + 1));
        s_dinv[t] = d;
        int node = own0 + t;
        if (node < N_NODES) dinv[node] = d;
    }
    __syncthreads();

    // matvec for owned nodes: thread-per-node, float4 x row (independent chains)
    if (t < BRANGE) {
        int node = own0 + t;
        if (node < N_NODES) {
            const float4* xr = (const float4*)(x + (size_t)node * N_FEATS);
            const float4* wr = (const float4*)w;
            float acc = 0.0f;
            #pragma unroll
            for (int k = 0; k < N_FEATS / 4; k++) {
                float4 v = xr[k];
                float4 u = wr[k];
                acc += v.x * u.x + v.y * u.y + v.z * u.z + v.w * u.w;
            }
            z0[node] = s_dinv[t] * acc;
        }
    }
}

// Hop: one WG per bucket; stream own records (uint2, coalesced), LDS f32
// accumulate over 196 owned nodes, finalize with self term + dinv scaling.
//   FINAL=false: out[i] = dinv^2 * (z[i] + sum)      (emits next z)
//   FINAL=true : out[i] = dinv   * (z[i] + sum) + b
template <bool FINAL>
__global__ void __launch_bounds__(HOPT) k_hop(
    const int* __restrict__ gcur, const unsigned* __restrict__ recs,
    const float* __restrict__ dinv, const float* __restrict__ zin,
    float* __restrict__ out, const float* __restrict__ bptr)
{
    __shared__ float acc[BRANGE];
    const int t = threadIdx.x;
    const int blk = blockIdx.x;
    if (t < BRANGE) acc[t] = 0.0f;
    __syncthreads();
    const int sz  = min(gcur[blk], CAPB);
    const int sz2 = sz >> 1;
    const uint2* rb2 = (const uint2*)(recs + (size_t)blk * CAPB);
    for (int e = t; e < sz2; e += HOPT) {
        uint2 r = rb2[e];
        atomicAdd(&acc[r.x >> 16], zin[r.x & 0xFFFFu]);
        atomicAdd(&acc[r.y >> 16], zin[r.y & 0xFFFFu]);
    }
    if (t == 0 && (sz & 1)) {
        unsigned r = recs[(size_t)blk * CAPB + sz - 1];
        atomicAdd(&acc[r >> 16], zin[r & 0xFFFFu]);
    }
    __syncthreads();
    if (t < BRANGE) {
        int node = blk * BRANGE + t;
        if (node < N_NODES) {
            float d = dinv[node];
            float v = zin[node] + acc[t];
            out[node] = FINAL ? (d * v + bptr[0]) : (d * d * v);
        }
    }
}

// ---------------- launch ----------------

extern "C" void kernel_launch(void* const* d_in, const int* in_sizes, int n_in,
                              void* d_out, int out_size, void* d_ws, size_t ws_size,
                              hipStream_t stream) {
    const float* x  = (const float*)d_in[0];   // [N, 64]
    const int*   ei = (const int*)d_in[1];     // [2, E]
    const float* W  = (const float*)d_in[2];   // [1, 64]
    const float* b  = (const float*)d_in[3];   // [1]
    float* out = (float*)d_out;                // [N]

    const int* row = ei;                       // sources
    const int* col = ei + N_EDGES;             // destinations

    // ws: gcur[256] | recs[NBUCK*CAPB u32] (4 MB) | dinv[N] | z0[N] | z1[N]
    int*      gcur = (int*)d_ws;
    unsigned* recs = (unsigned*)(gcur + NBUCK);
    float*    dinv = (float*)(recs + (size_t)NBUCK * CAPB);
    float*    z0   = dinv + N_NODES;
    float*    z1   = z0 + N_NODES;

    // zero bucket cursors via DMA memset (capture-safe; replaces a kernel dispatch)
    hipMemsetAsync(gcur, 0, NBUCK * sizeof(int), stream);

    k_bucketize<<<(EB4 + BZT - 1) / BZT, BZT, 0, stream>>>(row, col, gcur, recs);
    k_prep<<<NBUCK, 512, 0, stream>>>(gcur, recs, x, W, dinv, z0);

    k_hop<false><<<NBUCK, HOPT, 0, stream>>>(gcur, recs, dinv, z0, z1, nullptr); // hop 1
    k_hop<false><<<NBUCK, HOPT, 0, stream>>>(gcur, recs, dinv, z1, z0, nullptr); // hop 2
    k_hop<true ><<<NBUCK, HOPT, 0, stream>>>(gcur, recs, dinv, z0, out, b);      // hop 3
}